// Round 5
// baseline (30893.008 us; speedup 1.0000x reference)
//
#include <hip/hip_runtime.h>

#define T_STEPS 4096
#define IDIM 2048
#define HDIM 2048
#define G4DIM 8192

typedef __attribute__((ext_vector_type(8))) short short8;
typedef __attribute__((ext_vector_type(4))) float f32x4;
typedef __attribute__((ext_vector_type(2))) float f32x2;

__device__ __forceinline__ unsigned short f2bf(float f) {
  unsigned int u = __float_as_uint(f);
  u += 0x7fffu + ((u >> 16) & 1u);
  return (unsigned short)(u >> 16);
}
__device__ __forceinline__ float bf2f(unsigned short h) {
  return __uint_as_float(((unsigned int)h) << 16);
}

// C[M,N] = act( sum_k A[m,k]*B[n,k] + bias[n] )
// A: fp32 [M,K] row-major; B: fp32 [N,K] row-major (i.e. B^T form).
// Split-bf16: each fp32 -> hi+lo bf16; 3 MFMA passes (hi*hi + hi*lo + lo*hi)
// gives ~fp32-level accuracy at 1/3 of bf16 MFMA rate.
template <int ACT_SIGMOID, int OUT_BF16>
__global__ __launch_bounds__(256) void gemm_bt(
    const float* __restrict__ A, const float* __restrict__ B,
    const float* __restrict__ bias, void* __restrict__ Cout,
    int M, int N, int K)
{
  // 40 = 32 + 8 pad (16B) -> row stride 80 B = 20 banks: 2-way max (free)
  __shared__ short Ah[64][40];
  __shared__ short Al[64][40];
  __shared__ short Bh[64][40];
  __shared__ short Bl[64][40];
  const int tid  = threadIdx.x;
  const int wave = tid >> 6, lane = tid & 63;
  const int bn = blockIdx.x * 64, bm = blockIdx.y * 64;
  const int srow = tid >> 2, sc8 = (tid & 3) * 8;     // staging: 64 rows x 4 chunks of 8
  const int wm = (wave >> 1) * 32, wn = (wave & 1) * 32;
  const int lq = lane >> 4, lr = lane & 15;           // quad, index-in-tile
  f32x4 acc[2][2] = {};

  for (int k0 = 0; k0 < K; k0 += 32) {
    __syncthreads();
    {   // stage A tile (64x32 fp32 -> hi/lo bf16)
      const float* src = A + (size_t)(bm + srow) * K + k0 + sc8;
      float4 v0 = *(const float4*)(src);
      float4 v1 = *(const float4*)(src + 4);
      float vv[8] = {v0.x, v0.y, v0.z, v0.w, v1.x, v1.y, v1.z, v1.w};
      short8 vh, vl;
      #pragma unroll
      for (int i = 0; i < 8; ++i) {
        unsigned short hb = f2bf(vv[i]);
        vh[i] = (short)hb;
        vl[i] = (short)f2bf(vv[i] - bf2f(hb));
      }
      *(short8*)&Ah[srow][sc8] = vh;
      *(short8*)&Al[srow][sc8] = vl;
    }
    {   // stage B tile
      const float* src = B + (size_t)(bn + srow) * K + k0 + sc8;
      float4 v0 = *(const float4*)(src);
      float4 v1 = *(const float4*)(src + 4);
      float vv[8] = {v0.x, v0.y, v0.z, v0.w, v1.x, v1.y, v1.z, v1.w};
      short8 vh, vl;
      #pragma unroll
      for (int i = 0; i < 8; ++i) {
        unsigned short hb = f2bf(vv[i]);
        vh[i] = (short)hb;
        vl[i] = (short)f2bf(vv[i] - bf2f(hb));
      }
      *(short8*)&Bh[srow][sc8] = vh;
      *(short8*)&Bl[srow][sc8] = vl;
    }
    __syncthreads();

    short8 ah0 = *(const short8*)&Ah[wm +      lr][lq * 8];
    short8 al0 = *(const short8*)&Al[wm +      lr][lq * 8];
    short8 ah1 = *(const short8*)&Ah[wm + 16 + lr][lq * 8];
    short8 al1 = *(const short8*)&Al[wm + 16 + lr][lq * 8];
    short8 bh0 = *(const short8*)&Bh[wn +      lr][lq * 8];
    short8 bl0 = *(const short8*)&Bl[wn +      lr][lq * 8];
    short8 bh1 = *(const short8*)&Bh[wn + 16 + lr][lq * 8];
    short8 bl1 = *(const short8*)&Bl[wn + 16 + lr][lq * 8];

    acc[0][0] = __builtin_amdgcn_mfma_f32_16x16x32_bf16(ah0, bh0, acc[0][0], 0, 0, 0);
    acc[0][0] = __builtin_amdgcn_mfma_f32_16x16x32_bf16(ah0, bl0, acc[0][0], 0, 0, 0);
    acc[0][0] = __builtin_amdgcn_mfma_f32_16x16x32_bf16(al0, bh0, acc[0][0], 0, 0, 0);

    acc[0][1] = __builtin_amdgcn_mfma_f32_16x16x32_bf16(ah0, bh1, acc[0][1], 0, 0, 0);
    acc[0][1] = __builtin_amdgcn_mfma_f32_16x16x32_bf16(ah0, bl1, acc[0][1], 0, 0, 0);
    acc[0][1] = __builtin_amdgcn_mfma_f32_16x16x32_bf16(al0, bh1, acc[0][1], 0, 0, 0);

    acc[1][0] = __builtin_amdgcn_mfma_f32_16x16x32_bf16(ah1, bh0, acc[1][0], 0, 0, 0);
    acc[1][0] = __builtin_amdgcn_mfma_f32_16x16x32_bf16(ah1, bl0, acc[1][0], 0, 0, 0);
    acc[1][0] = __builtin_amdgcn_mfma_f32_16x16x32_bf16(al1, bh0, acc[1][0], 0, 0, 0);

    acc[1][1] = __builtin_amdgcn_mfma_f32_16x16x32_bf16(ah1, bh1, acc[1][1], 0, 0, 0);
    acc[1][1] = __builtin_amdgcn_mfma_f32_16x16x32_bf16(ah1, bl1, acc[1][1], 0, 0, 0);
    acc[1][1] = __builtin_amdgcn_mfma_f32_16x16x32_bf16(al1, bh1, acc[1][1], 0, 0, 0);
  }

  // epilogue: D row = (lane>>4)*4 + reg, col = lane&15
  #pragma unroll
  for (int mi = 0; mi < 2; ++mi) {
    #pragma unroll
    for (int ni = 0; ni < 2; ++ni) {
      #pragma unroll
      for (int rr = 0; rr < 4; ++rr) {
        int row = bm + wm + mi * 16 + lq * 4 + rr;
        int col = bn + wn + ni * 16 + lr;
        float v = acc[mi][ni][rr];
        if (bias) v += bias[col];
        if (ACT_SIGMOID) v = 1.f / (1.f + __expf(-v));
        if (OUT_BF16)
          ((unsigned short*)Cout)[(size_t)row * N + col] = f2bf(v);
        else
          ((float*)Cout)[(size_t)row * N + col] = v;
      }
    }
  }
}

// Persistent-weight LSTM scan, v6: v5 compute skeleton + SIGNAL/DATA SPLIT.
// v5 evidence: 580MB un-sourced HBM FETCH + 2MB/round chip-wide poll traffic
// (every thread agent-polling its own 8B of hs) => the poll storm congests
// L3/fabric and is itself the pace-setter. v6 topology:
//  * producers: agent atomic h-store (8 lanes), then ONE lane does a RELEASE
//    fetch_add on a group counter cnt[t][b>>3] (32 counters/step, 8 WGs per
//    group -> max 8-way RMW serialization per counter).
//  * consumers: ONLY wave0 polls the 128B counter row (lanes 0..31, relaxed,
//    s_sleep backoff; ACQUIRE agent fence on success), then publishes an LDS
//    token. Waves 1..15 spin on the LDS token (zero fabric traffic).
//  * h(t-1) is then read with plain coalesced dwordx2 loads -- exactly one
//    round, no retry, all lines freshly L3-resident.
//  Poll fabric traffic: 2MB/round -> 32KB/round. hs poison memset deleted
//  (hs never read before counter says it's written); cnt memset 512KB.
// Ordering: h-stores (agent) precede the RELEASE add (wave-level vmcnt
// drain); consumer: relaxed polls -> ACQUIRE agent fence -> LDS RELEASE
// token -> LDS ACQUIRE fence -> plain loads. Fresh addresses per step, so
// no stale-L2 hazard. Partials WAR: double-buffered, gated by the global
// dataflow chain exactly as v2/v5.
__global__ __launch_bounds__(1024, 4) void lstm_scan(
    const float* __restrict__ Whh,
    const float* __restrict__ b_ih, const float* __restrict__ b_hh,
    const unsigned short* __restrict__ gx,   // [T][8192] bf16
    float* __restrict__ hs,                  // [T][2048] fp32
    int* __restrict__ cnt)                   // [T][32] ints, zeroed
{
  const int b    = blockIdx.x;
  const int tid  = threadIdx.x;
  const int u    = tid & 7;       // unit within WG
  const int kc   = tid >> 3;      // K-chunk [0,128)
  const int wv   = tid >> 6;      // wave [0,16)
  const int lane = tid & 63;

  // weights: gate g, k in [kc*16, kc*16+16)
  f32x2 w2[4][8];
  #pragma unroll
  for (int g = 0; g < 4; ++g) {
    const float* wp = Whh + (size_t)(g * HDIM + b * 8 + u) * HDIM + kc * 16;
    #pragma unroll
    for (int i = 0; i < 4; ++i) {
      float4 v = *(const float4*)(wp + 4 * i);
      w2[g][2 * i]     = f32x2{v.x, v.y};
      w2[g][2 * i + 1] = f32x2{v.z, v.w};
    }
  }
  float bias_r = 0.f;
  if (tid < 32) {
    int br = (tid >> 3) * HDIM + b * 8 + (tid & 7);
    bias_r = b_ih[br] + b_hh[br];
  }
  float cval = 0.f;  // lanes tid<8 only

  __shared__ float h_lds[128 * 20];        // padded chunks: stride 20 dwords
  __shared__ float partials[2][32][18];    // [buf][gate-row][wave], stride 18
  __shared__ int   token;                  // highest step whose inputs are ready
  if (tid == 0) token = 0;                 // covered by t=0's __syncthreads
  unsigned int* hs_u = (unsigned int*)hs;

  // gx prefetch registers (tid<32 only); raw ushort so the vmcnt wait lands
  // at the (t+1) finalize use, a full step after issue.
  const unsigned short* gxp = gx + (tid >> 3) * HDIM + b * 8 + (tid & 7);
  unsigned short gxr_cur = 0, gxr_nxt = 0;
  if (tid < 32) gxr_cur = gxp[0];

  for (int t = 0; t < T_STEPS; ++t) {
    const int buf = t & 1;
    if (tid < 32 && t + 1 < T_STEPS)
      gxr_nxt = gxp[(size_t)(t + 1) * G4DIM];

    // ---- wait for h(t-1) ready, then ONE plain coalesced load ----
    f32x2 h2w;
    if (t > 0) {
      if (wv == 0) {
        // wave0: poll the 32 group counters (128B row), relaxed + backoff
        const int* cp = cnt + (size_t)(t - 1) * 32;
        for (;;) {
          int v = 8;
          if (lane < 32)
            v = __hip_atomic_load(cp + lane, __ATOMIC_RELAXED,
                                  __HIP_MEMORY_SCOPE_AGENT);
          if (__all(v == 8)) break;
          __builtin_amdgcn_s_sleep(1);
        }
        __builtin_amdgcn_fence(__ATOMIC_ACQUIRE, "agent");
        __hip_atomic_store(&token, t, __ATOMIC_RELEASE,
                           __HIP_MEMORY_SCOPE_WORKGROUP);
      } else {
        // waves 1..15: LDS token spin -- zero fabric traffic
        while (__hip_atomic_load(&token, __ATOMIC_RELAXED,
                                 __HIP_MEMORY_SCOPE_WORKGROUP) < t)
          __builtin_amdgcn_s_sleep(1);
        __builtin_amdgcn_fence(__ATOMIC_ACQUIRE, "workgroup");
      }
      float2 hv = *(const float2*)(hs + (size_t)(t - 1) * HDIM + tid * 2);
      h2w = f32x2{hv.x, hv.y};
    } else {
      h2w = f32x2{0.f, 0.f};
    }

    // stage into padded LDS; consumers of chunk kc are the 8 lanes that wrote
    // it (same wave) -> per-wave in-order DS pipe, no barrier needed.
    *(f32x2*)&h_lds[kc * 20 + u * 2] = h2w;

    f32x2 acc0{0.f, 0.f}, acc1{0.f, 0.f}, acc2{0.f, 0.f}, acc3{0.f, 0.f};
    #pragma unroll
    for (int i = 0; i < 4; ++i) {
      float4 hv = *(const float4*)&h_lds[kc * 20 + i * 4];
      f32x2 ha{hv.x, hv.y}, hb{hv.z, hv.w};
      acc0 += w2[0][2 * i] * ha;  acc0 += w2[0][2 * i + 1] * hb;
      acc1 += w2[1][2 * i] * ha;  acc1 += w2[1][2 * i + 1] * hb;
      acc2 += w2[2][2 * i] * ha;  acc2 += w2[2][2 * i + 1] * hb;
      acc3 += w2[3][2 * i] * ha;  acc3 += w2[3][2 * i + 1] * hb;
    }
    float s0 = acc0[0] + acc0[1];
    float s1 = acc1[0] + acc1[1];
    float s2 = acc2[0] + acc2[1];
    float s3 = acc3[0] + acc3[1];
    // fold the 8 K-chunks held by lanes {.., +8, .., +56} of this wave
    #pragma unroll
    for (int m = 8; m <= 32; m <<= 1) {
      s0 += __shfl_xor(s0, m, 64);
      s1 += __shfl_xor(s1, m, 64);
      s2 += __shfl_xor(s2, m, 64);
      s3 += __shfl_xor(s3, m, 64);
    }
    if ((tid & 56) == 0) {  // first 8 lanes of each wave
      // transposed store: row = gate-row, col = wave. Bank = (row*18+wv)%32;
      // for u=0..7 at fixed g: u*18%32 = {0,18,4,22,8,26,12,30} distinct.
      partials[buf][0 * 8 + u][wv] = s0;
      partials[buf][1 * 8 + u][wv] = s1;
      partials[buf][2 * 8 + u][wv] = s2;
      partials[buf][3 * 8 + u][wv] = s3;
    }
    __syncthreads();

    if (tid < 64) {  // wave 0 reduces + finalizes
      __builtin_amdgcn_s_setprio(1);
      float gval = 0.f;
      if (tid < 32) {
        float s = bf2f(gxr_cur) + bias_r;
        // 8x ds_read_b64 at row stride 18 dwords (72B): lane tid reads row
        // tid; bank = (tid*18 + 2i)%32, 2-way alias only (free).
        const float* pr = &partials[buf][tid][0];
        #pragma unroll
        for (int i = 0; i < 8; ++i) {
          float2 v = *(const float2*)(pr + 2 * i);
          s += v.x + v.y;
        }
        gval = s;
      }
      float g_i = __shfl(gval, tid);
      float g_f = __shfl(gval, tid + 8);
      float g_g = __shfl(gval, tid + 16);
      float g_o = __shfl(gval, tid + 24);
      if (tid < 8) {
        float is = 1.f / (1.f + __expf(-g_i));
        float fs = 1.f / (1.f + __expf(-g_f));
        float os = 1.f / (1.f + __expf(-g_o));
        float e2 = __expf(-2.f * fabsf(g_g));
        float tg = (1.f - e2) / (1.f + e2);
        tg = (g_g < 0.f) ? -tg : tg;
        float cn = fs * cval + is * tg;
        cval = cn;
        float ec = __expf(-2.f * fabsf(cn));
        float tc = (1.f - ec) / (1.f + ec);
        tc = (cn < 0.f) ? -tc : tc;
        float hn = os * tc;
        __hip_atomic_store(hs_u + (size_t)t * HDIM + b * 8 + tid,
                           __float_as_uint(hn),
                           __ATOMIC_RELAXED, __HIP_MEMORY_SCOPE_AGENT);
      }
      // signal: RELEASE add orders the wave's h-stores (vmcnt drain) before
      // the counter bump. One RMW per WG per step; 8 WGs share a counter.
      if (tid == 0)
        __hip_atomic_fetch_add(cnt + (size_t)t * 32 + (b >> 3), 1,
                               __ATOMIC_RELEASE, __HIP_MEMORY_SCOPE_AGENT);
      __builtin_amdgcn_s_setprio(0);
    }
    gxr_cur = gxr_nxt;
    // no trailing barrier: partials double-buffered; step t+2's writes are
    // gated by the global dataflow chain (our wave0's partials-read at t
    // happens-before its h(t) store -> cnt(t) -> everyone's token(t+1) ->
    // t+2 partial writes).
  }
}

extern "C" void kernel_launch(void* const* d_in, const int* in_sizes, int n_in,
                              void* d_out, int out_size, void* d_ws, size_t ws_size,
                              hipStream_t stream) {
  (void)in_sizes; (void)n_in; (void)out_size; (void)ws_size;
  const float* x    = (const float*)d_in[0];   // [1,4096,2048]
  const float* W_ih = (const float*)d_in[1];   // [8192,2048]
  const float* W_hh = (const float*)d_in[2];   // [8192,2048]
  const float* b_ih = (const float*)d_in[3];   // [8192]
  const float* b_hh = (const float*)d_in[4];   // [8192]
  const float* Wo   = (const float*)d_in[5];   // [2048,2048]
  const float* bo   = (const float*)d_in[6];   // [2048]
  float* out = (float*)d_out;

  char* ws = (char*)d_ws;
  unsigned short* gx = (unsigned short*)ws;                    // 64 MiB bf16
  float* hs = (float*)(ws + (size_t)T_STEPS * G4DIM * 2);      // 32 MiB fp32
  int*  cnt = (int*)(ws + (size_t)T_STEPS * G4DIM * 2
                        + (size_t)T_STEPS * HDIM * 4);         // 512 KiB

  // zero the per-step group counters (replaces the 32MB hs poison memset)
  hipMemsetAsync(cnt, 0, (size_t)T_STEPS * 32 * sizeof(int), stream);

  // gx = x @ W_ih^T  (biases folded into the scan)
  gemm_bt<0, 1><<<dim3(G4DIM / 64, T_STEPS / 64), 256, 0, stream>>>(
      x, W_ih, nullptr, gx, T_STEPS, G4DIM, IDIM);

  lstm_scan<<<256, 1024, 0, stream>>>(W_hh, b_ih, b_hh, gx, hs, cnt);

  // out = sigmoid(hs @ Wo^T + bo)
  gemm_bt<1, 0><<<dim3(IDIM / 64, T_STEPS / 64), 256, 0, stream>>>(
      hs, Wo, bo, out, T_STEPS, IDIM, HDIM);
}

// Round 6
// 11659.942 us; speedup vs baseline: 2.6495x; 2.6495x over previous
//
#include <hip/hip_runtime.h>

#define T_STEPS 4096
#define IDIM 2048
#define HDIM 2048
#define G4DIM 8192

typedef __attribute__((ext_vector_type(8))) short short8;
typedef __attribute__((ext_vector_type(4))) float f32x4;
typedef __attribute__((ext_vector_type(2))) float f32x2;

__device__ __forceinline__ unsigned short f2bf(float f) {
  unsigned int u = __float_as_uint(f);
  u += 0x7fffu + ((u >> 16) & 1u);
  return (unsigned short)(u >> 16);
}
__device__ __forceinline__ float bf2f(unsigned short h) {
  return __uint_as_float(((unsigned int)h) << 16);
}

// C[M,N] = act( sum_k A[m,k]*B[n,k] + bias[n] )
// A: fp32 [M,K] row-major; B: fp32 [N,K] row-major (i.e. B^T form).
// Split-bf16: each fp32 -> hi+lo bf16; 3 MFMA passes (hi*hi + hi*lo + lo*hi)
// gives ~fp32-level accuracy at 1/3 of bf16 MFMA rate.
template <int ACT_SIGMOID, int OUT_BF16>
__global__ __launch_bounds__(256) void gemm_bt(
    const float* __restrict__ A, const float* __restrict__ B,
    const float* __restrict__ bias, void* __restrict__ Cout,
    int M, int N, int K)
{
  // 40 = 32 + 8 pad (16B) -> row stride 80 B = 20 banks: 2-way max (free)
  __shared__ short Ah[64][40];
  __shared__ short Al[64][40];
  __shared__ short Bh[64][40];
  __shared__ short Bl[64][40];
  const int tid  = threadIdx.x;
  const int wave = tid >> 6, lane = tid & 63;
  const int bn = blockIdx.x * 64, bm = blockIdx.y * 64;
  const int srow = tid >> 2, sc8 = (tid & 3) * 8;     // staging: 64 rows x 4 chunks of 8
  const int wm = (wave >> 1) * 32, wn = (wave & 1) * 32;
  const int lq = lane >> 4, lr = lane & 15;           // quad, index-in-tile
  f32x4 acc[2][2] = {};

  for (int k0 = 0; k0 < K; k0 += 32) {
    __syncthreads();
    {   // stage A tile (64x32 fp32 -> hi/lo bf16)
      const float* src = A + (size_t)(bm + srow) * K + k0 + sc8;
      float4 v0 = *(const float4*)(src);
      float4 v1 = *(const float4*)(src + 4);
      float vv[8] = {v0.x, v0.y, v0.z, v0.w, v1.x, v1.y, v1.z, v1.w};
      short8 vh, vl;
      #pragma unroll
      for (int i = 0; i < 8; ++i) {
        unsigned short hb = f2bf(vv[i]);
        vh[i] = (short)hb;
        vl[i] = (short)f2bf(vv[i] - bf2f(hb));
      }
      *(short8*)&Ah[srow][sc8] = vh;
      *(short8*)&Al[srow][sc8] = vl;
    }
    {   // stage B tile
      const float* src = B + (size_t)(bn + srow) * K + k0 + sc8;
      float4 v0 = *(const float4*)(src);
      float4 v1 = *(const float4*)(src + 4);
      float vv[8] = {v0.x, v0.y, v0.z, v0.w, v1.x, v1.y, v1.z, v1.w};
      short8 vh, vl;
      #pragma unroll
      for (int i = 0; i < 8; ++i) {
        unsigned short hb = f2bf(vv[i]);
        vh[i] = (short)hb;
        vl[i] = (short)f2bf(vv[i] - bf2f(hb));
      }
      *(short8*)&Bh[srow][sc8] = vh;
      *(short8*)&Bl[srow][sc8] = vl;
    }
    __syncthreads();

    short8 ah0 = *(const short8*)&Ah[wm +      lr][lq * 8];
    short8 al0 = *(const short8*)&Al[wm +      lr][lq * 8];
    short8 ah1 = *(const short8*)&Ah[wm + 16 + lr][lq * 8];
    short8 al1 = *(const short8*)&Al[wm + 16 + lr][lq * 8];
    short8 bh0 = *(const short8*)&Bh[wn +      lr][lq * 8];
    short8 bl0 = *(const short8*)&Bl[wn +      lr][lq * 8];
    short8 bh1 = *(const short8*)&Bh[wn + 16 + lr][lq * 8];
    short8 bl1 = *(const short8*)&Bl[wn + 16 + lr][lq * 8];

    acc[0][0] = __builtin_amdgcn_mfma_f32_16x16x32_bf16(ah0, bh0, acc[0][0], 0, 0, 0);
    acc[0][0] = __builtin_amdgcn_mfma_f32_16x16x32_bf16(ah0, bl0, acc[0][0], 0, 0, 0);
    acc[0][0] = __builtin_amdgcn_mfma_f32_16x16x32_bf16(al0, bh0, acc[0][0], 0, 0, 0);

    acc[0][1] = __builtin_amdgcn_mfma_f32_16x16x32_bf16(ah0, bh1, acc[0][1], 0, 0, 0);
    acc[0][1] = __builtin_amdgcn_mfma_f32_16x16x32_bf16(ah0, bl1, acc[0][1], 0, 0, 0);
    acc[0][1] = __builtin_amdgcn_mfma_f32_16x16x32_bf16(al0, bh1, acc[0][1], 0, 0, 0);

    acc[1][0] = __builtin_amdgcn_mfma_f32_16x16x32_bf16(ah1, bh0, acc[1][0], 0, 0, 0);
    acc[1][0] = __builtin_amdgcn_mfma_f32_16x16x32_bf16(ah1, bl0, acc[1][0], 0, 0, 0);
    acc[1][0] = __builtin_amdgcn_mfma_f32_16x16x32_bf16(al1, bh0, acc[1][0], 0, 0, 0);

    acc[1][1] = __builtin_amdgcn_mfma_f32_16x16x32_bf16(ah1, bh1, acc[1][1], 0, 0, 0);
    acc[1][1] = __builtin_amdgcn_mfma_f32_16x16x32_bf16(ah1, bl1, acc[1][1], 0, 0, 0);
    acc[1][1] = __builtin_amdgcn_mfma_f32_16x16x32_bf16(al1, bh1, acc[1][1], 0, 0, 0);
  }

  // epilogue: D row = (lane>>4)*4 + reg, col = lane&15
  #pragma unroll
  for (int mi = 0; mi < 2; ++mi) {
    #pragma unroll
    for (int ni = 0; ni < 2; ++ni) {
      #pragma unroll
      for (int rr = 0; rr < 4; ++rr) {
        int row = bm + wm + mi * 16 + lq * 4 + rr;
        int col = bn + wn + ni * 16 + lr;
        float v = acc[mi][ni][rr];
        if (bias) v += bias[col];
        if (ACT_SIGMOID) v = 1.f / (1.f + __expf(-v));
        if (OUT_BF16)
          ((unsigned short*)Cout)[(size_t)row * N + col] = f2bf(v);
        else
          ((float*)Cout)[(size_t)row * N + col] = v;
      }
    }
  }
}

// Persistent-weight LSTM scan, v7 = v5 (best: per-thread data-poll with
// sentinel + sleep backoff + per-step barrier) + two critical-path cuts.
// v6 lesson (30ms regression): NEVER split signal from data -- the poll
// that succeeds must BE the data delivery (one L3 RT). Changes vs v5:
//  * POISON LINE WARMING: producer wave0, after storing h(t), also stores
//    0xAA poison to its 32B slice of hs[t+1]. Pulls the line into L3 one
//    full step ahead, so consumers' first poll of a line never pays an HBM
//    round trip (the old first-touch of ms-old evicted poison lines).
//    Ordering: poison(t+1) -> real-h(t+1) is same-thread same-address
//    program order; consumers see 0xAA (retry) or real data -- no new race.
//  * PARALLEL ACTIVATIONS: all 32 finalize lanes apply their own gate's
//    activation (sigmoid for i,f,o lanes; tanh for g lanes) in parallel,
//    then lanes 0..7 gather and do only c-update + one tanh. Cuts the
//    serial 5-transcendental chain (~200cy) ahead of the pace-setting
//    h-store to ~2.
// Everything else identical to v5 (gx reg prefetch, transposed [32][18]
// partials + ds_read_b64 sums, setprio around finalize, 8B single-load
// poll, per-step __syncthreads, double-buffered partials w/ dataflow WAR).
__global__ __launch_bounds__(1024, 4) void lstm_scan(
    const float* __restrict__ Whh,
    const float* __restrict__ b_ih, const float* __restrict__ b_hh,
    const unsigned short* __restrict__ gx,   // [T][8192] bf16
    float* __restrict__ hs)                  // [T][2048] fp32, poisoned 0xAA
{
  const int b   = blockIdx.x;
  const int tid = threadIdx.x;
  const int u   = tid & 7;       // unit within WG
  const int kc  = tid >> 3;      // K-chunk [0,128)
  const int wv  = tid >> 6;      // wave [0,16)

  // weights: gate g, k in [kc*16, kc*16+16)
  f32x2 w2[4][8];
  #pragma unroll
  for (int g = 0; g < 4; ++g) {
    const float* wp = Whh + (size_t)(g * HDIM + b * 8 + u) * HDIM + kc * 16;
    #pragma unroll
    for (int i = 0; i < 4; ++i) {
      float4 v = *(const float4*)(wp + 4 * i);
      w2[g][2 * i]     = f32x2{v.x, v.y};
      w2[g][2 * i + 1] = f32x2{v.z, v.w};
    }
  }
  float bias_r = 0.f;
  if (tid < 32) {
    int br = (tid >> 3) * HDIM + b * 8 + (tid & 7);
    bias_r = b_ih[br] + b_hh[br];
  }
  float cval = 0.f;  // lanes tid<8 only

  __shared__ float h_lds[128 * 20];        // padded chunks: stride 20 dwords
  __shared__ float partials[2][32][18];    // [buf][gate-row][wave], stride 18
  unsigned int* hs_u = (unsigned int*)hs;

  // gx prefetch registers (tid<32 only); raw ushort so the vmcnt wait lands
  // at the (t+1) finalize use, a full step after issue.
  const unsigned short* gxp = gx + (tid >> 3) * HDIM + b * 8 + (tid & 7);
  unsigned short gxr_cur = 0, gxr_nxt = 0;
  if (tid < 32) gxr_cur = gxp[0];

  for (int t = 0; t < T_STEPS; ++t) {
    const int buf = t & 1;
    if (tid < 32 && t + 1 < T_STEPS)
      gxr_nxt = gxp[(size_t)(t + 1) * G4DIM];

    // poll + load this thread's 2 h elements (global idx g0 = tid*2).
    // Single aligned 8B relaxed atomic load per round; first check has no
    // sleep, stragglers back off with s_sleep(1).
    f32x2 h2w;
    if (t > 0) {
      const unsigned long long* p =
          (const unsigned long long*)(hs_u + (size_t)(t - 1) * HDIM + tid * 2);
      for (;;) {
        unsigned long long v =
            __hip_atomic_load(p, __ATOMIC_RELAXED, __HIP_MEMORY_SCOPE_AGENT);
        unsigned int lo = (unsigned int)v, hi = (unsigned int)(v >> 32);
        if (lo != 0xAAAAAAAAu && hi != 0xAAAAAAAAu) {
          h2w = f32x2{__uint_as_float(lo), __uint_as_float(hi)};
          break;
        }
        __builtin_amdgcn_s_sleep(1);
      }
    } else {
      h2w = f32x2{0.f, 0.f};
    }

    // stage into padded LDS; consumers of chunk kc are the 8 lanes that wrote
    // it (same wave) -> per-wave in-order DS pipe, no barrier needed.
    *(f32x2*)&h_lds[kc * 20 + u * 2] = h2w;

    f32x2 acc0{0.f, 0.f}, acc1{0.f, 0.f}, acc2{0.f, 0.f}, acc3{0.f, 0.f};
    #pragma unroll
    for (int i = 0; i < 4; ++i) {
      float4 hv = *(const float4*)&h_lds[kc * 20 + i * 4];
      f32x2 ha{hv.x, hv.y}, hb{hv.z, hv.w};
      acc0 += w2[0][2 * i] * ha;  acc0 += w2[0][2 * i + 1] * hb;
      acc1 += w2[1][2 * i] * ha;  acc1 += w2[1][2 * i + 1] * hb;
      acc2 += w2[2][2 * i] * ha;  acc2 += w2[2][2 * i + 1] * hb;
      acc3 += w2[3][2 * i] * ha;  acc3 += w2[3][2 * i + 1] * hb;
    }
    float s0 = acc0[0] + acc0[1];
    float s1 = acc1[0] + acc1[1];
    float s2 = acc2[0] + acc2[1];
    float s3 = acc3[0] + acc3[1];
    // fold the 8 K-chunks held by lanes {.., +8, .., +56} of this wave
    #pragma unroll
    for (int m = 8; m <= 32; m <<= 1) {
      s0 += __shfl_xor(s0, m, 64);
      s1 += __shfl_xor(s1, m, 64);
      s2 += __shfl_xor(s2, m, 64);
      s3 += __shfl_xor(s3, m, 64);
    }
    if ((tid & 56) == 0) {  // first 8 lanes of each wave
      // transposed store: row = gate-row, col = wave. Bank = (row*18+wv)%32;
      // for u=0..7 at fixed g: u*18%32 = {0,18,4,22,8,26,12,30} distinct.
      partials[buf][0 * 8 + u][wv] = s0;
      partials[buf][1 * 8 + u][wv] = s1;
      partials[buf][2 * 8 + u][wv] = s2;
      partials[buf][3 * 8 + u][wv] = s3;
    }
    __syncthreads();

    if (tid < 64) {  // wave 0 reduces + finalizes
      __builtin_amdgcn_s_setprio(1);
      float gval = 0.f;
      if (tid < 32) {
        float s = bf2f(gxr_cur) + bias_r;
        // 8x ds_read_b64 at row stride 18 dwords (72B): lane tid reads row
        // tid; bank = (tid*18 + 2i)%32, 2-way alias only (free).
        const float* pr = &partials[buf][tid][0];
        #pragma unroll
        for (int i = 0; i < 8; ++i) {
          float2 v = *(const float2*)(pr + 2 * i);
          s += v.x + v.y;
        }
        gval = s;
      }
      // parallel activations: each of the 32 lanes applies ITS gate's
      // nonlinearity (i,f,o lanes: sigmoid; g lanes 16..23: tanh).
      float act;
      if (tid >= 16 && tid < 24) {
        float e2 = __expf(-2.f * fabsf(gval));
        float tg = (1.f - e2) / (1.f + e2);
        act = (gval < 0.f) ? -tg : tg;
      } else {
        act = 1.f / (1.f + __expf(-gval));
      }
      float a_i = __shfl(act, tid);
      float a_f = __shfl(act, tid + 8);
      float a_g = __shfl(act, tid + 16);
      float a_o = __shfl(act, tid + 24);
      if (tid < 8) {
        float cn = a_f * cval + a_i * a_g;
        cval = cn;
        float ec = __expf(-2.f * fabsf(cn));
        float tc = (1.f - ec) / (1.f + ec);
        tc = (cn < 0.f) ? -tc : tc;
        float hn = a_o * tc;
        __hip_atomic_store(hs_u + (size_t)t * HDIM + b * 8 + tid,
                           __float_as_uint(hn),
                           __ATOMIC_RELAXED, __HIP_MEMORY_SCOPE_AGENT);
        // warm next step's line: poison-store our slice of hs[t+1] so
        // consumers' polls hit L3, never HBM. Same-thread same-address
        // program order vs the real h(t+1) store next iteration.
        if (t + 1 < T_STEPS)
          __hip_atomic_store(hs_u + (size_t)(t + 1) * HDIM + b * 8 + tid,
                             0xAAAAAAAAu,
                             __ATOMIC_RELAXED, __HIP_MEMORY_SCOPE_AGENT);
      }
      __builtin_amdgcn_s_setprio(0);
    }
    gxr_cur = gxr_nxt;
    // no trailing barrier: partials double-buffered; step t+2's writes are
    // gated by the global dataflow chain (our wave0's partials-read at t
    // happens-before its h(t) store -> producers' h(t+1) -> t+2 polls).
  }
}

extern "C" void kernel_launch(void* const* d_in, const int* in_sizes, int n_in,
                              void* d_out, int out_size, void* d_ws, size_t ws_size,
                              hipStream_t stream) {
  (void)in_sizes; (void)n_in; (void)out_size; (void)ws_size;
  const float* x    = (const float*)d_in[0];   // [1,4096,2048]
  const float* W_ih = (const float*)d_in[1];   // [8192,2048]
  const float* W_hh = (const float*)d_in[2];   // [8192,2048]
  const float* b_ih = (const float*)d_in[3];   // [8192]
  const float* b_hh = (const float*)d_in[4];   // [8192]
  const float* Wo   = (const float*)d_in[5];   // [2048,2048]
  const float* bo   = (const float*)d_in[6];   // [2048]
  float* out = (float*)d_out;

  char* ws = (char*)d_ws;
  unsigned short* gx = (unsigned short*)ws;               // 64 MiB bf16
  float* hs = (float*)(ws + (size_t)T_STEPS * G4DIM * 2); // 32 MiB fp32

  // our own in-graph poison: the scan's dataflow sync depends on it
  hipMemsetAsync(hs, 0xAA, (size_t)T_STEPS * HDIM * sizeof(float), stream);

  // gx = x @ W_ih^T  (biases folded into the scan)
  gemm_bt<0, 1><<<dim3(G4DIM / 64, T_STEPS / 64), 256, 0, stream>>>(
      x, W_ih, nullptr, gx, T_STEPS, G4DIM, IDIM);

  lstm_scan<<<256, 1024, 0, stream>>>(W_hh, b_ih, b_hh, gx, hs);

  // out = sigmoid(hs @ Wo^T + bo)
  gemm_bt<1, 0><<<dim3(IDIM / 64, T_STEPS / 64), 256, 0, stream>>>(
      hs, Wo, bo, out, T_STEPS, IDIM, HDIM);
}

// Round 7
// 10894.269 us; speedup vs baseline: 2.8357x; 1.0703x over previous
//
#include <hip/hip_runtime.h>

#define T_STEPS 4096
#define IDIM 2048
#define HDIM 2048
#define G4DIM 8192

typedef __attribute__((ext_vector_type(8))) short short8;
typedef __attribute__((ext_vector_type(4))) float f32x4;
typedef __attribute__((ext_vector_type(2))) float f32x2;

__device__ __forceinline__ unsigned short f2bf(float f) {
  unsigned int u = __float_as_uint(f);
  u += 0x7fffu + ((u >> 16) & 1u);
  return (unsigned short)(u >> 16);
}
__device__ __forceinline__ float bf2f(unsigned short h) {
  return __uint_as_float(((unsigned int)h) << 16);
}

// C[M,N] = act( sum_k A[m,k]*B[n,k] + bias[n] )
// A: fp32 [M,K] row-major; B: fp32 [N,K] row-major (i.e. B^T form).
// Split-bf16: each fp32 -> hi+lo bf16; 3 MFMA passes (hi*hi + hi*lo + lo*hi)
// gives ~fp32-level accuracy at 1/3 of bf16 MFMA rate.
template <int ACT_SIGMOID, int OUT_BF16>
__global__ __launch_bounds__(256) void gemm_bt(
    const float* __restrict__ A, const float* __restrict__ B,
    const float* __restrict__ bias, void* __restrict__ Cout,
    int M, int N, int K)
{
  // 40 = 32 + 8 pad (16B) -> row stride 80 B = 20 banks: 2-way max (free)
  __shared__ short Ah[64][40];
  __shared__ short Al[64][40];
  __shared__ short Bh[64][40];
  __shared__ short Bl[64][40];
  const int tid  = threadIdx.x;
  const int wave = tid >> 6, lane = tid & 63;
  const int bn = blockIdx.x * 64, bm = blockIdx.y * 64;
  const int srow = tid >> 2, sc8 = (tid & 3) * 8;     // staging: 64 rows x 4 chunks of 8
  const int wm = (wave >> 1) * 32, wn = (wave & 1) * 32;
  const int lq = lane >> 4, lr = lane & 15;           // quad, index-in-tile
  f32x4 acc[2][2] = {};

  for (int k0 = 0; k0 < K; k0 += 32) {
    __syncthreads();
    {   // stage A tile (64x32 fp32 -> hi/lo bf16)
      const float* src = A + (size_t)(bm + srow) * K + k0 + sc8;
      float4 v0 = *(const float4*)(src);
      float4 v1 = *(const float4*)(src + 4);
      float vv[8] = {v0.x, v0.y, v0.z, v0.w, v1.x, v1.y, v1.z, v1.w};
      short8 vh, vl;
      #pragma unroll
      for (int i = 0; i < 8; ++i) {
        unsigned short hb = f2bf(vv[i]);
        vh[i] = (short)hb;
        vl[i] = (short)f2bf(vv[i] - bf2f(hb));
      }
      *(short8*)&Ah[srow][sc8] = vh;
      *(short8*)&Al[srow][sc8] = vl;
    }
    {   // stage B tile
      const float* src = B + (size_t)(bn + srow) * K + k0 + sc8;
      float4 v0 = *(const float4*)(src);
      float4 v1 = *(const float4*)(src + 4);
      float vv[8] = {v0.x, v0.y, v0.z, v0.w, v1.x, v1.y, v1.z, v1.w};
      short8 vh, vl;
      #pragma unroll
      for (int i = 0; i < 8; ++i) {
        unsigned short hb = f2bf(vv[i]);
        vh[i] = (short)hb;
        vl[i] = (short)f2bf(vv[i] - bf2f(hb));
      }
      *(short8*)&Bh[srow][sc8] = vh;
      *(short8*)&Bl[srow][sc8] = vl;
    }
    __syncthreads();

    short8 ah0 = *(const short8*)&Ah[wm +      lr][lq * 8];
    short8 al0 = *(const short8*)&Al[wm +      lr][lq * 8];
    short8 ah1 = *(const short8*)&Ah[wm + 16 + lr][lq * 8];
    short8 al1 = *(const short8*)&Al[wm + 16 + lr][lq * 8];
    short8 bh0 = *(const short8*)&Bh[wn +      lr][lq * 8];
    short8 bl0 = *(const short8*)&Bl[wn +      lr][lq * 8];
    short8 bh1 = *(const short8*)&Bh[wn + 16 + lr][lq * 8];
    short8 bl1 = *(const short8*)&Bl[wn + 16 + lr][lq * 8];

    acc[0][0] = __builtin_amdgcn_mfma_f32_16x16x32_bf16(ah0, bh0, acc[0][0], 0, 0, 0);
    acc[0][0] = __builtin_amdgcn_mfma_f32_16x16x32_bf16(ah0, bl0, acc[0][0], 0, 0, 0);
    acc[0][0] = __builtin_amdgcn_mfma_f32_16x16x32_bf16(al0, bh0, acc[0][0], 0, 0, 0);

    acc[0][1] = __builtin_amdgcn_mfma_f32_16x16x32_bf16(ah0, bh1, acc[0][1], 0, 0, 0);
    acc[0][1] = __builtin_amdgcn_mfma_f32_16x16x32_bf16(ah0, bl1, acc[0][1], 0, 0, 0);
    acc[0][1] = __builtin_amdgcn_mfma_f32_16x16x32_bf16(al0, bh1, acc[0][1], 0, 0, 0);

    acc[1][0] = __builtin_amdgcn_mfma_f32_16x16x32_bf16(ah1, bh0, acc[1][0], 0, 0, 0);
    acc[1][0] = __builtin_amdgcn_mfma_f32_16x16x32_bf16(ah1, bl0, acc[1][0], 0, 0, 0);
    acc[1][0] = __builtin_amdgcn_mfma_f32_16x16x32_bf16(al1, bh0, acc[1][0], 0, 0, 0);

    acc[1][1] = __builtin_amdgcn_mfma_f32_16x16x32_bf16(ah1, bh1, acc[1][1], 0, 0, 0);
    acc[1][1] = __builtin_amdgcn_mfma_f32_16x16x32_bf16(ah1, bl1, acc[1][1], 0, 0, 0);
    acc[1][1] = __builtin_amdgcn_mfma_f32_16x16x32_bf16(al1, bh1, acc[1][1], 0, 0, 0);
  }

  // epilogue: D row = (lane>>4)*4 + reg, col = lane&15
  #pragma unroll
  for (int mi = 0; mi < 2; ++mi) {
    #pragma unroll
    for (int ni = 0; ni < 2; ++ni) {
      #pragma unroll
      for (int rr = 0; rr < 4; ++rr) {
        int row = bm + wm + mi * 16 + lq * 4 + rr;
        int col = bn + wn + ni * 16 + lr;
        float v = acc[mi][ni][rr];
        if (bias) v += bias[col];
        if (ACT_SIGMOID) v = 1.f / (1.f + __expf(-v));
        if (OUT_BF16)
          ((unsigned short*)Cout)[(size_t)row * N + col] = f2bf(v);
        else
          ((float*)Cout)[(size_t)row * N + col] = v;
      }
    }
  }
}

// Persistent-weight LSTM scan, v8 = v7 + PHASE-LOCKED POLL ROUNDS.
// v7 post-mortem: means account for ~2400cy/step; observed ~6300. The gap is
// VARIANCE: 4096 independent sleep-backoff poll loops (period ~700cy, random
// phase) x per-WG 16-wave barrier (releases at the MAX of 16 detects) x
// chip straggler-max integrate up to a full period+ of phase noise per step.
// v8: on poll failure, sleep until the next 32-tick boundary of the GLOBAL
// 100MHz s_memrealtime counter (32 ticks = 320ns ~ 770 core cy). All pending
// waves chip-wide then re-poll in the same ~150cy window -> detect-max ~
// detect-min + RT jitter; barrier spread and straggler-max collapse. First
// poll is immediate (arrived data pays zero). Mean lag unchanged (~period/2);
// only the variance -- what the max-of-4096 integrates -- is removed.
// Thundering herd is bounded: <=2MB per synchronized round / ~34TB/s L3 ~
// 150cy of service. Everything else identical to v7.
__global__ __launch_bounds__(1024, 4) void lstm_scan(
    const float* __restrict__ Whh,
    const float* __restrict__ b_ih, const float* __restrict__ b_hh,
    const unsigned short* __restrict__ gx,   // [T][8192] bf16
    float* __restrict__ hs)                  // [T][2048] fp32, poisoned 0xAA
{
  const int b   = blockIdx.x;
  const int tid = threadIdx.x;
  const int u   = tid & 7;       // unit within WG
  const int kc  = tid >> 3;      // K-chunk [0,128)
  const int wv  = tid >> 6;      // wave [0,16)

  // weights: gate g, k in [kc*16, kc*16+16)
  f32x2 w2[4][8];
  #pragma unroll
  for (int g = 0; g < 4; ++g) {
    const float* wp = Whh + (size_t)(g * HDIM + b * 8 + u) * HDIM + kc * 16;
    #pragma unroll
    for (int i = 0; i < 4; ++i) {
      float4 v = *(const float4*)(wp + 4 * i);
      w2[g][2 * i]     = f32x2{v.x, v.y};
      w2[g][2 * i + 1] = f32x2{v.z, v.w};
    }
  }
  float bias_r = 0.f;
  if (tid < 32) {
    int br = (tid >> 3) * HDIM + b * 8 + (tid & 7);
    bias_r = b_ih[br] + b_hh[br];
  }
  float cval = 0.f;  // lanes tid<8 only

  __shared__ float h_lds[128 * 20];        // padded chunks: stride 20 dwords
  __shared__ float partials[2][32][18];    // [buf][gate-row][wave], stride 18
  unsigned int* hs_u = (unsigned int*)hs;

  // gx prefetch registers (tid<32 only); raw ushort so the vmcnt wait lands
  // at the (t+1) finalize use, a full step after issue.
  const unsigned short* gxp = gx + (tid >> 3) * HDIM + b * 8 + (tid & 7);
  unsigned short gxr_cur = 0, gxr_nxt = 0;
  if (tid < 32) gxr_cur = gxp[0];

  for (int t = 0; t < T_STEPS; ++t) {
    const int buf = t & 1;
    if (tid < 32 && t + 1 < T_STEPS)
      gxr_nxt = gxp[(size_t)(t + 1) * G4DIM];

    // poll + load this thread's 2 h elements (global idx g0 = tid*2).
    // Single aligned 8B relaxed atomic load; first check immediate. On
    // failure, PHASE-LOCK: sleep until the next 32-tick boundary of the
    // chip-global 100MHz realtime counter, so all pending waves re-poll
    // in the same narrow window (kills phase-noise straggler-max).
    f32x2 h2w;
    if (t > 0) {
      const unsigned long long* p =
          (const unsigned long long*)(hs_u + (size_t)(t - 1) * HDIM + tid * 2);
      for (;;) {
        unsigned long long v =
            __hip_atomic_load(p, __ATOMIC_RELAXED, __HIP_MEMORY_SCOPE_AGENT);
        unsigned int lo = (unsigned int)v, hi = (unsigned int)(v >> 32);
        if (lo != 0xAAAAAAAAu && hi != 0xAAAAAAAAu) {
          h2w = f32x2{__uint_as_float(lo), __uint_as_float(hi)};
          break;
        }
        {  // align to next global 32-tick (≈320ns) boundary
          unsigned long long tgt =
              (__builtin_amdgcn_s_memrealtime() | 31ull) + 1ull;
          do {
            __builtin_amdgcn_s_sleep(1);
          } while (__builtin_amdgcn_s_memrealtime() < tgt);
        }
      }
    } else {
      h2w = f32x2{0.f, 0.f};
    }

    // stage into padded LDS; consumers of chunk kc are the 8 lanes that wrote
    // it (same wave) -> per-wave in-order DS pipe, no barrier needed.
    *(f32x2*)&h_lds[kc * 20 + u * 2] = h2w;

    f32x2 acc0{0.f, 0.f}, acc1{0.f, 0.f}, acc2{0.f, 0.f}, acc3{0.f, 0.f};
    #pragma unroll
    for (int i = 0; i < 4; ++i) {
      float4 hv = *(const float4*)&h_lds[kc * 20 + i * 4];
      f32x2 ha{hv.x, hv.y}, hb{hv.z, hv.w};
      acc0 += w2[0][2 * i] * ha;  acc0 += w2[0][2 * i + 1] * hb;
      acc1 += w2[1][2 * i] * ha;  acc1 += w2[1][2 * i + 1] * hb;
      acc2 += w2[2][2 * i] * ha;  acc2 += w2[2][2 * i + 1] * hb;
      acc3 += w2[3][2 * i] * ha;  acc3 += w2[3][2 * i + 1] * hb;
    }
    float s0 = acc0[0] + acc0[1];
    float s1 = acc1[0] + acc1[1];
    float s2 = acc2[0] + acc2[1];
    float s3 = acc3[0] + acc3[1];
    // fold the 8 K-chunks held by lanes {.., +8, .., +56} of this wave
    #pragma unroll
    for (int m = 8; m <= 32; m <<= 1) {
      s0 += __shfl_xor(s0, m, 64);
      s1 += __shfl_xor(s1, m, 64);
      s2 += __shfl_xor(s2, m, 64);
      s3 += __shfl_xor(s3, m, 64);
    }
    if ((tid & 56) == 0) {  // first 8 lanes of each wave
      // transposed store: row = gate-row, col = wave. Bank = (row*18+wv)%32;
      // for u=0..7 at fixed g: u*18%32 = {0,18,4,22,8,26,12,30} distinct.
      partials[buf][0 * 8 + u][wv] = s0;
      partials[buf][1 * 8 + u][wv] = s1;
      partials[buf][2 * 8 + u][wv] = s2;
      partials[buf][3 * 8 + u][wv] = s3;
    }
    __syncthreads();

    if (tid < 64) {  // wave 0 reduces + finalizes
      __builtin_amdgcn_s_setprio(1);
      float gval = 0.f;
      if (tid < 32) {
        float s = bf2f(gxr_cur) + bias_r;
        // 8x ds_read_b64 at row stride 18 dwords (72B): lane tid reads row
        // tid; bank = (tid*18 + 2i)%32, 2-way alias only (free).
        const float* pr = &partials[buf][tid][0];
        #pragma unroll
        for (int i = 0; i < 8; ++i) {
          float2 v = *(const float2*)(pr + 2 * i);
          s += v.x + v.y;
        }
        gval = s;
      }
      // parallel activations: each of the 32 lanes applies ITS gate's
      // nonlinearity (i,f,o lanes: sigmoid; g lanes 16..23: tanh).
      float act;
      if (tid >= 16 && tid < 24) {
        float e2 = __expf(-2.f * fabsf(gval));
        float tg = (1.f - e2) / (1.f + e2);
        act = (gval < 0.f) ? -tg : tg;
      } else {
        act = 1.f / (1.f + __expf(-gval));
      }
      float a_i = __shfl(act, tid);
      float a_f = __shfl(act, tid + 8);
      float a_g = __shfl(act, tid + 16);
      float a_o = __shfl(act, tid + 24);
      if (tid < 8) {
        float cn = a_f * cval + a_i * a_g;
        cval = cn;
        float ec = __expf(-2.f * fabsf(cn));
        float tc = (1.f - ec) / (1.f + ec);
        tc = (cn < 0.f) ? -tc : tc;
        float hn = a_o * tc;
        __hip_atomic_store(hs_u + (size_t)t * HDIM + b * 8 + tid,
                           __float_as_uint(hn),
                           __ATOMIC_RELAXED, __HIP_MEMORY_SCOPE_AGENT);
        // warm next step's line: poison-store our slice of hs[t+1] so
        // consumers' polls hit L3, never HBM. Same-thread same-address
        // program order vs the real h(t+1) store next iteration.
        if (t + 1 < T_STEPS)
          __hip_atomic_store(hs_u + (size_t)(t + 1) * HDIM + b * 8 + tid,
                             0xAAAAAAAAu,
                             __ATOMIC_RELAXED, __HIP_MEMORY_SCOPE_AGENT);
      }
      __builtin_amdgcn_s_setprio(0);
    }
    gxr_cur = gxr_nxt;
    // no trailing barrier: partials double-buffered; step t+2's writes are
    // gated by the global dataflow chain (our wave0's partials-read at t
    // happens-before its h(t) store -> producers' h(t+1) -> t+2 polls).
  }
}

extern "C" void kernel_launch(void* const* d_in, const int* in_sizes, int n_in,
                              void* d_out, int out_size, void* d_ws, size_t ws_size,
                              hipStream_t stream) {
  (void)in_sizes; (void)n_in; (void)out_size; (void)ws_size;
  const float* x    = (const float*)d_in[0];   // [1,4096,2048]
  const float* W_ih = (const float*)d_in[1];   // [8192,2048]
  const float* W_hh = (const float*)d_in[2];   // [8192,2048]
  const float* b_ih = (const float*)d_in[3];   // [8192]
  const float* b_hh = (const float*)d_in[4];   // [8192]
  const float* Wo   = (const float*)d_in[5];   // [2048,2048]
  const float* bo   = (const float*)d_in[6];   // [2048]
  float* out = (float*)d_out;

  char* ws = (char*)d_ws;
  unsigned short* gx = (unsigned short*)ws;               // 64 MiB bf16
  float* hs = (float*)(ws + (size_t)T_STEPS * G4DIM * 2); // 32 MiB fp32

  // our own in-graph poison: the scan's dataflow sync depends on it
  hipMemsetAsync(hs, 0xAA, (size_t)T_STEPS * HDIM * sizeof(float), stream);

  // gx = x @ W_ih^T  (biases folded into the scan)
  gemm_bt<0, 1><<<dim3(G4DIM / 64, T_STEPS / 64), 256, 0, stream>>>(
      x, W_ih, nullptr, gx, T_STEPS, G4DIM, IDIM);

  lstm_scan<<<256, 1024, 0, stream>>>(W_hh, b_ih, b_hh, gx, hs);

  // out = sigmoid(hs @ Wo^T + bo)
  gemm_bt<1, 0><<<dim3(IDIM / 64, T_STEPS / 64), 256, 0, stream>>>(
      hs, Wo, bo, out, T_STEPS, IDIM, HDIM);
}